// Round 9
// baseline (41705.350 us; speedup 1.0000x reference)
//
#include <hip/hip_runtime.h>
#include <hip/hip_bf16.h>
#include <math.h>

#define B_  128
#define T_  256
#define DIN 512
#define H_  1024

typedef __attribute__((ext_vector_type(8))) short bf16x8;
typedef __attribute__((ext_vector_type(4))) float f32x4;

#define GLD_LDS16(gsrc, ldst) \
  __builtin_amdgcn_global_load_lds((const __attribute__((address_space(1))) void*)(gsrc), \
                                   (__attribute__((address_space(3))) void*)(ldst), 16, 0, 0)

__device__ __forceinline__ void split_bf16(float v, __hip_bfloat16* hi, __hip_bfloat16* lo) {
    __hip_bfloat16 h = __float2bfloat16(v);
    *hi = h;
    *lo = __float2bfloat16(v - __bfloat162float(h));
}

__device__ __forceinline__ float sigmoidf_(float x) { return 1.f / (1.f + expf(-x)); }

// ---- coherent (L3-served, cross-XCD) helpers ------------------------------
__device__ __forceinline__ void cohld1_issue(float* dst, const float* ptr) {
    asm volatile("global_load_dword %0, %1, off sc0 sc1" : "=v"(*dst) : "v"(ptr));
}
__device__ __forceinline__ void cohst1(float* ptr, float v) {
    asm volatile("global_store_dword %0, %1, off sc0 sc1" :: "v"(ptr), "v"(v) : "memory");
}
#define COH_WAIT() do { asm volatile("s_waitcnt vmcnt(0)" ::: "memory"); \
                        __builtin_amdgcn_sched_barrier(0); } while (0)

// split 4 fp32 -> hi/lo bf16 planes (plain stores -> local XCD L2)
__device__ __forceinline__ void store_split4(uint4 cv, unsigned short* dh, unsigned short* dl) {
    float f0 = __uint_as_float(cv.x), f1 = __uint_as_float(cv.y);
    float f2 = __uint_as_float(cv.z), f3 = __uint_as_float(cv.w);
    __hip_bfloat16 b0 = __float2bfloat16(f0), b1 = __float2bfloat16(f1);
    __hip_bfloat16 b2 = __float2bfloat16(f2), b3 = __float2bfloat16(f3);
    __hip_bfloat16 c0 = __float2bfloat16(f0 - __bfloat162float(b0));
    __hip_bfloat16 c1 = __float2bfloat16(f1 - __bfloat162float(b1));
    __hip_bfloat16 c2 = __float2bfloat16(f2 - __bfloat162float(b2));
    __hip_bfloat16 c3 = __float2bfloat16(f3 - __bfloat162float(b3));
    uint2 H, L;
    H.x = (unsigned)*(unsigned short*)&b0 | ((unsigned)*(unsigned short*)&b1 << 16);
    H.y = (unsigned)*(unsigned short*)&b2 | ((unsigned)*(unsigned short*)&b3 << 16);
    L.x = (unsigned)*(unsigned short*)&c0 | ((unsigned)*(unsigned short*)&c1 << 16);
    L.y = (unsigned)*(unsigned short*)&c2 | ((unsigned)*(unsigned short*)&c3 << 16);
    *(uint2*)dh = H;
    *(uint2*)dl = L;
}

// --------------------------- small prep kernels ----------------------------
__global__ void bias_sum_k(const float* __restrict__ a, const float* __restrict__ b,
                           float* __restrict__ o, int n) {
    int i = blockIdx.x * blockDim.x + threadIdx.x;
    if (i < n) o[i] = a[i] + b[i];
}

__global__ void detect_mask_k(const int* __restrict__ m, int nwords, int* __restrict__ flag) {
    __shared__ int bad;
    if (threadIdx.x == 0) bad = 0;
    __syncthreads();
    for (int i = threadIdx.x; i < nwords; i += blockDim.x) {
        unsigned v = (unsigned)m[i];
        if (v > 1u) bad = 1;
    }
    __syncthreads();
    if (threadIdx.x == 0) flag[0] = bad ? 0 : 1;  // 1 => int32 mask, 0 => u8 mask
}

__global__ void cvt_split_k(const float* __restrict__ s, __hip_bfloat16* __restrict__ hi,
                            __hip_bfloat16* __restrict__ lo, int n) {
    int i = blockIdx.x * 256 + threadIdx.x;
    if (i < n) split_bf16(s[i], hi + i, lo + i);
}

__global__ void wg_split_k(const float* __restrict__ Wih, const float* __restrict__ Whh,
                           __hip_bfloat16* __restrict__ Wh, __hip_bfloat16* __restrict__ Wl) {
    int i = blockIdx.x * 256 + threadIdx.x;           // over 4096*1536
    int n = i / 1536, c = i - n * 1536;
    float v = (c < DIN) ? Wih[n * DIN + c] : Whh[n * H_ + (c - DIN)];
    split_bf16(v, Wh + i, Wl + i);
}

// --------------------------- fused persistent kernel -----------------------
constexpr int APL = 128 * 64 * 2;          // 16 KB per A plane
constexpr int BPL = 32 * 64 * 2;           // 4 KB per B plane
constexpr int BUFB = 2 * APL + 2 * BPL;    // 40 KB
constexpr int LDSZ = 3 * BUFB;             // 120 KB -> 1 block/CU
constexpr int SCRE = 1 << 20;              // scratch stride per XCD (elems)

struct P {
    const float* input; const float* ctx; const void* srcmask;
    const float* bsum; float* cbuf;
    float* gpart; float* qpart; float* opart;
    float* pacc; float* pm; float* ps;
    float* hmaster; float* hymaster; float* wcmaster;
    const int* mflag; unsigned* cnt; unsigned* xbar; unsigned* xpop;
    const __hip_bfloat16 *Wgh, *Wgl, *Wah, *Wal, *Woh, *Wol;
    unsigned short* scr;
    float* out; float* hf; float* cf;
};

// grid barrier: relaxed agent atomics; data flows via sc0sc1/L3 or local L2.
#define GBAR() do { \
    __syncthreads(); \
    if (tid == 0) { \
        __hip_atomic_fetch_add(&p.cnt[slot], 1u, __ATOMIC_RELAXED, __HIP_MEMORY_SCOPE_AGENT); \
        while (__hip_atomic_load(&p.cnt[slot], __ATOMIC_RELAXED, __HIP_MEMORY_SCOPE_AGENT) < 256u) \
            __builtin_amdgcn_s_sleep(8); \
    } \
    ++slot; \
    __syncthreads(); \
  } while (0)

// per-XCD barrier (population-counted -> correct for any block distribution)
#define XBAR() do { \
    __syncthreads(); \
    if (tid == 0) { \
        unsigned* ctr_ = p.xbar + xcc * 768 + xslot; \
        __hip_atomic_fetch_add(ctr_, 1u, __ATOMIC_RELAXED, __HIP_MEMORY_SCOPE_AGENT); \
        while (__hip_atomic_load(ctr_, __ATOMIC_RELAXED, __HIP_MEMORY_SCOPE_AGENT) < pop) \
            __builtin_amdgcn_s_sleep(2); \
    } \
    ++xslot; \
    __syncthreads(); \
  } while (0)

// copy a 128*1024 fp32 master (L3) -> local-XCD hi/lo bf16 planes (L2)
#define COPY_MASTER(SRCP, DH, DL) do { \
    if (pop == 32u) { \
        uint4 cv_[4]; \
        _Pragma("unroll") \
        for (int i_ = 0; i_ < 4; ++i_) { \
            long c_ = rr * 256 + tid + i_ * 8192; \
            asm volatile("global_load_dwordx4 %0, %1, off sc0 sc1" \
                         : "=v"(cv_[i_]) : "v"((const float*)(SRCP) + 4 * c_)); \
        } \
        COH_WAIT(); \
        _Pragma("unroll") \
        for (int i_ = 0; i_ < 4; ++i_) { \
            long c_ = rr * 256 + tid + i_ * 8192; \
            store_split4(cv_[i_], (DH) + 4 * c_, (DL) + 4 * c_); \
        } \
    } else { \
        for (long c_ = rr * 256 + tid; c_ < 32768; c_ += (long)pop * 256) { \
            uint4 v_; \
            asm volatile("global_load_dwordx4 %0, %1, off sc0 sc1" \
                         : "=v"(v_) : "v"((const float*)(SRCP) + 4 * c_)); \
            COH_WAIT(); \
            store_split4(v_, (DH) + 4 * c_, (DL) + 4 * c_); \
        } \
    } \
} while (0)

// copy x_t slice (fp32 input, read-only cached) -> local hi/lo planes
#define COPY_X() do { \
    if (pop == 32u) { \
        uint4 cv_[2]; \
        _Pragma("unroll") \
        for (int i_ = 0; i_ < 2; ++i_) { \
            long c_ = rr * 256 + tid + i_ * 8192; \
            long e_ = 4 * c_, b_ = e_ >> 9, col_ = e_ & 511; \
            const float* sp_ = p.input + (b_ * T_ + t) * DIN + col_; \
            asm volatile("global_load_dwordx4 %0, %1, off" : "=v"(cv_[i_]) : "v"(sp_)); \
        } \
        COH_WAIT(); \
        _Pragma("unroll") \
        for (int i_ = 0; i_ < 2; ++i_) { \
            long c_ = rr * 256 + tid + i_ * 8192; \
            store_split4(cv_[i_], sxh + 4 * c_, sxl + 4 * c_); \
        } \
    } else { \
        for (long c_ = rr * 256 + tid; c_ < 16384; c_ += (long)pop * 256) { \
            long e_ = 4 * c_, b_ = e_ >> 9, col_ = e_ & 511; \
            const float* sp_ = p.input + (b_ * T_ + t) * DIN + col_; \
            uint4 v_; \
            asm volatile("global_load_dwordx4 %0, %1, off" : "=v"(v_) : "v"(sp_)); \
            COH_WAIT(); \
            store_split4(v_, sxh + 4 * c_, sxl + 4 * c_); \
        } \
    } \
} while (0)

// ---- GEMM building blocks: A-state from local-XCD scratch via sc0 (L2) ----
#define GP_ISSUE_A(KT) { \
    const int kbi_ = kbase_ + (KT) * 64; \
    _Pragma("unroll") \
    for (int pp = 0; pp < 2; ++pp) { \
        const unsigned short* A1p_ = pp ? A1l_ : A1h_; \
        const unsigned short* A2p_ = pp ? A2l_ : A2h_; \
        _Pragma("unroll") \
        for (int j = 0; j < 4; ++j) { \
            int c_ = j * 256 + tid; \
            int row_ = c_ >> 3, sl_ = c_ & 7; \
            int e_ = kbi_ + ((sl_ ^ (row_ & 7)) << 3); \
            const unsigned short* src_ = (e_ < K1_) ? (A1p_ + (long)row_ * lda1_ + e_) \
                                                    : (A2p_ + (long)row_ * lda2_ + (e_ - K1_)); \
            asm volatile("global_load_dwordx4 %0, %1, off sc0" \
                         : "=v"(rA[pp][j]) : "v"(src_)); \
        } \
    } }

#define GP_WRITE_A(BUF) { \
    char* wb_ = lds + (BUF) * BUFB; \
    _Pragma("unroll") \
    for (int pp = 0; pp < 2; ++pp) \
        _Pragma("unroll") \
        for (int j = 0; j < 4; ++j) \
            *(uint4*)(wb_ + pp * APL + (j * 256 + tid) * 16) = rA[pp][j]; \
    }

#define GP_ISSUE_B(KT, BUF) { \
    char* bb_ = lds + (BUF) * BUFB; \
    const int kbi_ = kbase_ + (KT) * 64; \
    int row_ = tid >> 3, sl_ = tid & 7; \
    int e_ = kbi_ + ((sl_ ^ (row_ & 7)) << 3); \
    _Pragma("unroll") \
    for (int pp = 0; pp < 2; ++pp) { \
        const __hip_bfloat16* src_ = (pp ? Wl_ : Wh_) + (long)(n0_ + row_) * ldw_ + e_; \
        GLD_LDS16(src_, bb_ + 2 * APL + pp * BPL + ((tid & 192) << 4)); \
    } }

// plane-fused split-bf16 GEMM phase (hh, lh, hl) -> Cpart[KSP] via sc0sc1
#define GEMM_PHASE(NT, NB, KSP, A1H, A1L, LDA1, K1V, A2H, A2L, LDA2, WHP, WLP, LDW, CP, LDC, PSTRIDE) \
  { \
    const int n0_ = (NB) * 32; \
    const int kbase_ = (KSP) * ((NT) * 64); \
    const int wm_ = (w >> 1) * 64, wn_ = (w & 1) * 16; \
    const unsigned short* A1h_ = (A1H); \
    const unsigned short* A1l_ = (A1L); \
    const unsigned short* A2h_ = (A2H); \
    const unsigned short* A2l_ = (A2L); \
    const long lda1_ = (LDA1), lda2_ = (LDA2), ldw_ = (LDW); \
    const int K1_ = (K1V); \
    const __hip_bfloat16* Wh_ = (WHP); \
    const __hip_bfloat16* Wl_ = (WLP); \
    uint4 rA[2][4]; \
    f32x4 acc[4] = {}; \
    GP_ISSUE_A(0); \
    GP_ISSUE_B(0, 0); \
    asm volatile("s_waitcnt vmcnt(2)" ::: "memory"); \
    __builtin_amdgcn_sched_barrier(0); \
    GP_WRITE_A(0); \
    GP_ISSUE_A(1); \
    GP_ISSUE_B(1, 1); \
    for (int kt = 0; kt < (NT); ++kt) { \
        asm volatile("s_waitcnt vmcnt(0) lgkmcnt(0)" ::: "memory"); \
        __builtin_amdgcn_s_barrier(); \
        __builtin_amdgcn_sched_barrier(0); \
        if (kt + 1 < (NT)) GP_WRITE_A((kt + 1) % 3); \
        if (kt + 2 < (NT)) { GP_ISSUE_A(kt + 2); GP_ISSUE_B(kt + 2, (kt + 2) % 3); } \
        const char* base = lds + (kt % 3) * BUFB; \
        _Pragma("unroll") \
        for (int ks = 0; ks < 2; ++ks) { \
            bf16x8 afh[4], afl[4], bh, bl; \
            _Pragma("unroll") \
            for (int mi = 0; mi < 4; ++mi) { \
                int row = wm_ + mi * 16 + (l & 15); \
                int sl2 = (l >> 4) + ks * 4; \
                int off = row * 128 + ((sl2 ^ (row & 7)) << 4); \
                afh[mi] = *(const bf16x8*)(base + off); \
                afl[mi] = *(const bf16x8*)(base + APL + off); \
            } \
            { \
                int row = wn_ + (l & 15); \
                int sl2 = (l >> 4) + ks * 4; \
                int off = row * 128 + ((sl2 ^ (row & 7)) << 4); \
                bh = *(const bf16x8*)(base + 2 * APL + off); \
                bl = *(const bf16x8*)(base + 2 * APL + BPL + off); \
            } \
            _Pragma("unroll") \
            for (int mi = 0; mi < 4; ++mi) { \
                acc[mi] = __builtin_amdgcn_mfma_f32_16x16x32_bf16(afh[mi], bh, acc[mi], 0, 0, 0); \
                acc[mi] = __builtin_amdgcn_mfma_f32_16x16x32_bf16(afl[mi], bh, acc[mi], 0, 0, 0); \
                acc[mi] = __builtin_amdgcn_mfma_f32_16x16x32_bf16(afh[mi], bl, acc[mi], 0, 0, 0); \
            } \
        } \
    } \
    float* Cb = (CP) + (long)(KSP) * (PSTRIDE); \
    const int n = n0_ + wn_ + (l & 15); \
    _Pragma("unroll") \
    for (int mi = 0; mi < 4; ++mi) { \
        int mbase = wm_ + mi * 16 + (l >> 4) * 4; \
        _Pragma("unroll") \
        for (int r = 0; r < 4; ++r) \
            cohst1(Cb + (long)(mbase + r) * (LDC) + n, acc[mi][r]); \
    } \
  }

__global__ __launch_bounds__(256, 1)
void fused_k(P p)
{
    __shared__ __attribute__((aligned(16))) char lds[LDSZ];
    __shared__ int xcc_s, rank_s, pop_s;
    const int blk = blockIdx.x;      // 0..255
    const int tid = threadIdx.x;
    const int l = tid & 63, w = tid >> 6;
    unsigned slot = 0, xslot = 0;

    // ---- topology discovery: real XCD id + rank claim ----
    unsigned xccr;
    asm volatile("s_getreg_b32 %0, hwreg(HW_REG_XCC_ID)" : "=s"(xccr));
    if (tid == 0) {
        xcc_s = (int)xccr;
        rank_s = (int)__hip_atomic_fetch_add(&p.xpop[xccr], 1u, __ATOMIC_RELAXED,
                                             __HIP_MEMORY_SCOPE_AGENT);
    }
    __syncthreads();
    const int xcc = xcc_s;
    const int rr = rank_s;
    GBAR();                      // slot 0: all population claims visible
    if (tid == 0)
        pop_s = (int)__hip_atomic_load(&p.xpop[xcc], __ATOMIC_RELAXED, __HIP_MEMORY_SCOPE_AGENT);
    __syncthreads();
    const unsigned pop = (unsigned)pop_s;

    // per-XCD scratch planes (only ever touched by this XCD -> L2-local)
    unsigned short* scr = p.scr + (size_t)xcc * SCRE;
    unsigned short* sxh = scr;               // [128][512]
    unsigned short* sxl = scr + 65536;
    unsigned short* shh = scr + 131072;      // [128][1024] h_tilde
    unsigned short* shl = scr + 262144;
    unsigned short* syh = scr + 393216;      // [128][1024] hy
    unsigned short* syl = scr + 524288;
    unsigned short* swh = scr + 655360;      // [128][1024] wctx
    unsigned short* swl = scr + 786432;

    for (int t = 0; t < T_; ++t) {
        // ---- copy state into local-XCD scratch, then G ----
        COPY_X();
        COPY_MASTER(p.hmaster, shh, shl);
        XBAR();

        // ---- G: gates partials  [x_t | h] @ Wg^T   K=1536, Ksplit=2, NT=12
        GEMM_PHASE(12, (blk & 127), (blk >> 7),
                   sxh, sxl, 512, 512,
                   shh, shl, 1024,
                   p.Wgh, p.Wgl, (DIN + H_),
                   p.gpart, (4 * H_), ((long)B_ * 4 * H_));
        GBAR();

        // ---- C: LSTM cell (+bias reduce) -> hy master
        {
            float gv[16];
            int idxA[2];
            #pragma unroll
            for (int i = 0; i < 2; ++i) {
                int idx = blk * 512 + i * 256 + tid;
                idxA[i] = idx;
                int b = idx >> 10, j = idx & 1023;
                const float* g0 = p.gpart + ((long)b << 12) + j;
                const float* g1 = g0 + (long)B_ * 4 * H_;
                cohld1_issue(&gv[i * 8 + 0], g0);
                cohld1_issue(&gv[i * 8 + 1], g0 + 1024);
                cohld1_issue(&gv[i * 8 + 2], g0 + 2048);
                cohld1_issue(&gv[i * 8 + 3], g0 + 3072);
                cohld1_issue(&gv[i * 8 + 4], g1);
                cohld1_issue(&gv[i * 8 + 5], g1 + 1024);
                cohld1_issue(&gv[i * 8 + 6], g1 + 2048);
                cohld1_issue(&gv[i * 8 + 7], g1 + 3072);
            }
            COH_WAIT();
            #pragma unroll
            for (int i = 0; i < 2; ++i) {
                int idx = idxA[i];
                int j = idx & 1023;
                float ig = sigmoidf_(gv[i * 8 + 0] + gv[i * 8 + 4] + p.bsum[j]);
                float fg = sigmoidf_(gv[i * 8 + 1] + gv[i * 8 + 5] + p.bsum[1024 + j]);
                float gg = tanhf    (gv[i * 8 + 2] + gv[i * 8 + 6] + p.bsum[2048 + j]);
                float og = sigmoidf_(gv[i * 8 + 3] + gv[i * 8 + 7] + p.bsum[3072 + j]);
                float c = fg * p.cbuf[idx] + ig * gg;
                float h = og * tanhf(c);
                p.cbuf[idx] = c;
                cohst1(p.hymaster + idx, h);
                if (t == T_ - 1) p.cf[idx] = c;
            }
        }
        GBAR();

        // ---- copy hy -> local scratch, then Q ----
        COPY_MASTER(p.hymaster, syh, syl);
        XBAR();

        // ---- Q: q partials  hy @ Wa^T   K=1024, Ksplit=4, NT=4 (128 blocks)
        if (blk < 128) {
            GEMM_PHASE(4, (blk & 31), (blk >> 5),
                       syh, syl, 1024, 1024,
                       syh, syl, 1024,
                       p.Wah, p.Wal, H_,
                       p.qpart, H_, ((long)B_ * H_));
        }
        GBAR();

        // ---- A: attention partial over half the L range
        {
            const int b = blk >> 1, half = blk & 1;
            const float* cb = p.ctx + (long)b * (T_ * H_);
            const int mode = p.mflag[0];

            float qt[64];
            #pragma unroll
            for (int j = 0; j < 16; ++j) {
                const float* qp = p.qpart + (long)b * H_ + l + j * 64;
                #pragma unroll
                for (int ss = 0; ss < 4; ++ss)
                    cohld1_issue(&qt[j * 4 + ss], qp + (long)ss * (B_ * H_));
            }
            COH_WAIT();
            float rq[16];
            #pragma unroll
            for (int j = 0; j < 16; ++j)
                rq[j] = (qt[j * 4] + qt[j * 4 + 1]) + (qt[j * 4 + 2] + qt[j * 4 + 3]);

            float m = -INFINITY, s = 0.f, acc[16] = {};
            const int base = half * 128;
            for (int li = base + w; li < base + 128; li += 4) {
                bool msk = mode ? (((const int*)p.srcmask)[b * T_ + li] != 0)
                                : (((const unsigned char*)p.srcmask)[b * T_ + li] != 0);
                if (msk) continue;
                const float* cr = cb + (long)li * H_;
                float rc[16], d = 0.f;
                #pragma unroll
                for (int j = 0; j < 16; ++j) { rc[j] = cr[l + j * 64]; d += rc[j] * rq[j]; }
                #pragma unroll
                for (int off = 1; off < 64; off <<= 1) d += __shfl_xor(d, off);
                float mn = fmaxf(m, d);
                float f = expf(m - mn);
                float pp2 = expf(d - mn);
                s = s * f + pp2;
                #pragma unroll
                for (int j = 0; j < 16; ++j) acc[j] = acc[j] * f + pp2 * rc[j];
                m = mn;
            }

            float (*sacc)[H_] = (float (*)[H_])lds;
            float (*sms)[2]   = (float (*)[2])(lds + 4 * H_ * sizeof(float));
            __syncthreads();
            #pragma unroll
            for (int j = 0; j < 16; ++j) sacc[w][l + j * 64] = acc[j];
            if (l == 0) { sms[w][0] = m; sms[w][1] = s; }
            __syncthreads();

            float M = fmaxf(fmaxf(sms[0][0], sms[1][0]), fmaxf(sms[2][0], sms[3][0]));
            float fw[4], S = 0.f;
            #pragma unroll
            for (int ww = 0; ww < 4; ++ww) {
                fw[ww] = (sms[ww][0] == -INFINITY) ? 0.f : expf(sms[ww][0] - M);
                S += fw[ww] * sms[ww][1];
            }
            int ph = b * 2 + half;
            for (int k = tid; k < H_; k += 256) {
                float a = sacc[0][k] * fw[0] + sacc[1][k] * fw[1] + sacc[2][k] * fw[2] + sacc[3][k] * fw[3];
                cohst1(p.pacc + (long)ph * H_ + k, a);
            }
            if (tid == 0) { cohst1(p.pm + ph, M); cohst1(p.ps + ph, S); }
        }
        GBAR();

        // ---- A2: combine halves -> wctx master
        {
            float av[12];
            int idxA[2];
            #pragma unroll
            for (int i = 0; i < 2; ++i) {
                int idx = blk * 512 + i * 256 + tid;
                idxA[i] = idx;
                int b = idx >> 10, k = idx & 1023;
                cohld1_issue(&av[i * 6 + 0], p.pacc + (long)(2 * b) * H_ + k);
                cohld1_issue(&av[i * 6 + 1], p.pacc + (long)(2 * b + 1) * H_ + k);
                cohld1_issue(&av[i * 6 + 2], p.pm + 2 * b);
                cohld1_issue(&av[i * 6 + 3], p.pm + 2 * b + 1);
                cohld1_issue(&av[i * 6 + 4], p.ps + 2 * b);
                cohld1_issue(&av[i * 6 + 5], p.ps + 2 * b + 1);
            }
            COH_WAIT();
            #pragma unroll
            for (int i = 0; i < 2; ++i) {
                int idx = idxA[i];
                float m0 = av[i * 6 + 2], m1 = av[i * 6 + 3];
                float M = fmaxf(m0, m1);
                float f0 = (m0 == -INFINITY) ? 0.f : expf(m0 - M);
                float f1 = (m1 == -INFINITY) ? 0.f : expf(m1 - M);
                float S = f0 * av[i * 6 + 4] + f1 * av[i * 6 + 5];
                float v = (av[i * 6 + 0] * f0 + av[i * 6 + 1] * f1) / S;
                cohst1(p.wcmaster + idx, v);
            }
        }
        GBAR();

        // ---- copy wctx -> local scratch, then O ----
        COPY_MASTER(p.wcmaster, swh, swl);
        XBAR();

        // ---- O: out partials  [wctx|hy] @ Wo^T   K=2048, Ksplit=8, NT=4
        GEMM_PHASE(4, (blk & 31), (blk >> 5),
                   swh, swl, 1024, 1024,
                   syh, syl, 1024,
                   p.Woh, p.Wol, (2 * H_),
                   p.opart, H_, ((long)B_ * H_));
        GBAR();

        // ---- R: reduce + tanh -> h master, output slice, (h_f)
        {
            float ov[16];
            int idxA[2];
            #pragma unroll
            for (int i = 0; i < 2; ++i) {
                int idx = blk * 512 + i * 256 + tid;
                idxA[i] = idx;
                #pragma unroll
                for (int ss = 0; ss < 8; ++ss)
                    cohld1_issue(&ov[i * 8 + ss], p.opart + idx + (long)ss * (B_ * H_));
            }
            COH_WAIT();
            #pragma unroll
            for (int i = 0; i < 2; ++i) {
                int idx = idxA[i];
                int b = idx >> 10, j = idx & 1023;
                float v = 0.f;
                #pragma unroll
                for (int ss = 0; ss < 8; ++ss) v += ov[i * 8 + ss];
                v = tanhf(v);
                cohst1(p.hmaster + idx, v);
                p.out[(long)b * (T_ * H_) + (long)t * H_ + j] = v;
                if (t == T_ - 1) p.hf[idx] = v;
            }
        }
        GBAR();
    }
}

// --------------------------- launcher --------------------------------------
extern "C" void kernel_launch(void* const* d_in, const int* in_sizes, int n_in,
                              void* d_out, int out_size, void* d_ws, size_t ws_size,
                              hipStream_t stream)
{
    const float* input  = (const float*)d_in[0];
    const float* h0     = (const float*)d_in[1];
    const float* c0     = (const float*)d_in[2];
    const float* ctx    = (const float*)d_in[3];
    const void*  srcmask= d_in[4];
    const float* W_ih   = (const float*)d_in[5];
    const float* W_hh   = (const float*)d_in[6];
    const float* b_ih   = (const float*)d_in[7];
    const float* b_hh   = (const float*)d_in[8];
    const float* W_attn = (const float*)d_in[9];
    const float* W_out  = (const float*)d_in[10];

    constexpr int B = B_, T = T_, D = DIN, H = H_;

    // -------- workspace --------
    float* f = (float*)d_ws;
    float* bsum    = f; f += 4 * H;
    float* cbuf    = f; f += (size_t)B * H;
    float* gpart   = f; f += (size_t)2 * B * 4 * H;
    float* qpart   = f; f += (size_t)4 * B * H;
    float* opart   = f; f += (size_t)8 * B * H;
    float* pacc    = f; f += (size_t)2 * B * H;
    float* pm      = f; f += 256;
    float* ps      = f; f += 256;
    float* hmaster = f; f += (size_t)B * H;
    float* hymaster= f; f += (size_t)B * H;
    float* wcmaster= f; f += (size_t)B * H;
    int*   mflag   = (int*)f; f += 64;
    unsigned* cnt  = (unsigned*)f; f += 2048;          // GBAR slots
    unsigned* xbar = (unsigned*)f; f += 6144;          // 8 XCD x 768 slots
    unsigned* xpop = (unsigned*)f; f += 16;
    __hip_bfloat16* p = (__hip_bfloat16*)f;
    __hip_bfloat16* Wgh = p; p += (size_t)4 * H * (D + H);
    __hip_bfloat16* Wgl = p; p += (size_t)4 * H * (D + H);
    __hip_bfloat16* Wah = p; p += (size_t)H * H;
    __hip_bfloat16* Wal = p; p += (size_t)H * H;
    __hip_bfloat16* Woh = p; p += (size_t)H * 2 * H;
    __hip_bfloat16* Wol = p; p += (size_t)H * 2 * H;
    unsigned short* scr = (unsigned short*)p;          // 8 XCD x 1M elems (16 MB)

    float* out = (float*)d_out;
    float* hf  = out + (size_t)B * T * H;
    float* cf  = hf + (size_t)B * H;

    // -------- prep --------
    hipMemsetAsync(cnt, 0, (2048 + 6144 + 16) * sizeof(unsigned), stream);
    hipMemcpyAsync(cbuf, c0, (size_t)B * H * sizeof(float), hipMemcpyDeviceToDevice, stream);
    hipMemcpyAsync(hmaster, h0, (size_t)B * H * sizeof(float), hipMemcpyDeviceToDevice, stream);
    bias_sum_k<<<dim3(16), dim3(256), 0, stream>>>(b_ih, b_hh, bsum, 4 * H);
    detect_mask_k<<<dim3(1), dim3(256), 0, stream>>>((const int*)srcmask, B * T / 4, mflag);
    wg_split_k<<<dim3(4 * H * (D + H) / 256), dim3(256), 0, stream>>>(W_ih, W_hh, Wgh, Wgl);
    cvt_split_k<<<dim3(H * H / 256), dim3(256), 0, stream>>>(W_attn, Wah, Wal, H * H);
    cvt_split_k<<<dim3(H * 2 * H / 256), dim3(256), 0, stream>>>(W_out, Woh, Wol, H * 2 * H);

    // -------- persistent fused kernel (1 block/CU via 120KB LDS) --------
    P prm;
    prm.input = input; prm.ctx = ctx; prm.srcmask = srcmask;
    prm.bsum = bsum; prm.cbuf = cbuf;
    prm.gpart = gpart; prm.qpart = qpart; prm.opart = opart;
    prm.pacc = pacc; prm.pm = pm; prm.ps = ps;
    prm.hmaster = hmaster; prm.hymaster = hymaster; prm.wcmaster = wcmaster;
    prm.mflag = mflag; prm.cnt = cnt; prm.xbar = xbar; prm.xpop = xpop;
    prm.Wgh = Wgh; prm.Wgl = Wgl; prm.Wah = Wah; prm.Wal = Wal;
    prm.Woh = Woh; prm.Wol = Wol;
    prm.scr = scr;
    prm.out = out; prm.hf = hf; prm.cf = cf;

    fused_k<<<dim3(256), dim3(256), 0, stream>>>(prm);
}

// Round 10
// 21532.265 us; speedup vs baseline: 1.9369x; 1.9369x over previous
//
#include <hip/hip_runtime.h>
#include <hip/hip_bf16.h>
#include <math.h>

#define B_  128
#define T_  256
#define DIN 512
#define H_  1024

typedef __attribute__((ext_vector_type(8))) short bf16x8;
typedef __attribute__((ext_vector_type(4))) float f32x4;

#define GLD_LDS16(gsrc, ldst) \
  __builtin_amdgcn_global_load_lds((const __attribute__((address_space(1))) void*)(gsrc), \
                                   (__attribute__((address_space(3))) void*)(ldst), 16, 0, 0)

#define WAITVM_(n) asm volatile("s_waitcnt vmcnt(" #n ")" ::: "memory")
#define WAITVM(n) WAITVM_(n)

__device__ __forceinline__ void split_bf16(float v, __hip_bfloat16* hi, __hip_bfloat16* lo) {
    __hip_bfloat16 h = __float2bfloat16(v);
    *hi = h;
    *lo = __float2bfloat16(v - __bfloat162float(h));
}

__device__ __forceinline__ float sigmoidf_(float x) { return 1.f / (1.f + expf(-x)); }

// --------------------------- small prep kernels ----------------------------
__global__ void bsum_perm_k(const float* __restrict__ bi, const float* __restrict__ bh,
                            float* __restrict__ o) {
    int c = blockIdx.x * 256 + threadIdx.x;            // 4096, permuted c = j*4+g
    int srow = ((c & 3) << 10) | (c >> 2);
    o[c] = bi[srow] + bh[srow];
}

__global__ void detect_mask_k(const int* __restrict__ m, int nwords, int* __restrict__ flag) {
    __shared__ int bad;
    if (threadIdx.x == 0) bad = 0;
    __syncthreads();
    for (int i = threadIdx.x; i < nwords; i += blockDim.x) {
        unsigned v = (unsigned)m[i];
        if (v > 1u) bad = 1;
    }
    __syncthreads();
    if (threadIdx.x == 0) flag[0] = bad ? 0 : 1;  // 1 => int32 mask, 0 => u8 mask
}

__global__ void cvt_split_k(const float* __restrict__ s, __hip_bfloat16* __restrict__ hi,
                            __hip_bfloat16* __restrict__ lo, int n) {
    int i = blockIdx.x * 256 + threadIdx.x;
    if (i < n) split_bf16(s[i], hi + i, lo + i);
}

// permuted combined weight: row c=j*4+g of [W_ih | W_hh], bf16 hi/lo planes
__global__ void wgp_split_k(const float* __restrict__ Wih, const float* __restrict__ Whh,
                            __hip_bfloat16* __restrict__ Wh, __hip_bfloat16* __restrict__ Wl) {
    long i = (long)blockIdx.x * 256 + threadIdx.x;     // 4096*1536
    int c = (int)(i / 1536), k = (int)(i - (long)c * 1536);
    int srow = ((c & 3) << 10) | (c >> 2);
    float v = (k < DIN) ? Wih[(long)srow * DIN + k] : Whh[(long)srow * H_ + (k - DIN)];
    split_bf16(v, Wh + i, Wl + i);
}

__global__ void cvtx_k(const float* __restrict__ xsrc, __hip_bfloat16* __restrict__ xh,
                       __hip_bfloat16* __restrict__ xl) {
    int i = blockIdx.x * 256 + threadIdx.x;
    int b = i >> 9, c = i & 511;
    split_bf16(xsrc[(long)b * (T_ * DIN) + c], xh + i, xl + i);
}

// --------------------------- GEMM core -------------------------------------
constexpr int APL = 128 * 64 * 2;          // 16 KB per A plane
constexpr int BPL = 32 * 64 * 2;           // 4 KB per B plane slot
constexpr int BUFB = 2 * APL + 2 * BPL;    // 40 KB
constexpr int LDSZ = 3 * BUFB;             // 120 KB

// plane-fused split-bf16 GEMM core (hh, lh, hl): leaves acc/n0_/wm_/wn_ in scope.
// requires: lds (named __shared__ char[]), tid, l, w.
#define GEMM_CORE(NT, NW2, BNV, VMID, NB, KSP, A1H, A1L, LDA1, K1V, A2H, A2L, LDA2, WHP, WLP, LDW) \
    const int n0_ = (NB) * (BNV); \
    const int kbase_ = (KSP) * ((NT) * 64); \
    const int wm_ = (NW2) ? (w >> 1) * 64 : w * 32; \
    const int wn_ = (NW2) ? (w & 1) * 16 : 0; \
    auto stage = [&](int buf, int kt) { \
        char* base = lds + buf * BUFB; \
        const int kb = kbase_ + kt * 64; \
        _Pragma("unroll") \
        for (int pp = 0; pp < 2; ++pp) { \
            const __hip_bfloat16* A1 = pp ? (A1L) : (A1H); \
            const __hip_bfloat16* A2 = pp ? (A2L) : (A2H); \
            _Pragma("unroll") \
            for (int j = 0; j < 4; ++j) { \
                int c = j * 256 + tid; \
                int row = c >> 3, sl2 = c & 7; \
                int e = kb + ((sl2 ^ (row & 7)) << 3); \
                const __hip_bfloat16* src = (e < (K1V)) ? (A1 + (long)row * (LDA1) + e) \
                                                        : (A2 + (long)row * (LDA2) + (e - (K1V))); \
                GLD_LDS16(src, base + pp * APL + ((j * 256 + (tid & 192)) << 4)); \
            } \
            if (tid < (BNV) * 8) { \
                int row = tid >> 3, sl2 = tid & 7; \
                int e = kb + ((sl2 ^ (row & 7)) << 3); \
                const __hip_bfloat16* src = (pp ? (WLP) : (WHP)) + (long)(n0_ + row) * (LDW) + e; \
                GLD_LDS16(src, base + 2 * APL + pp * BPL + ((tid & 192) << 4)); \
            } \
        } \
    }; \
    f32x4 acc[4] = {}; \
    stage(0, 0); \
    if ((NT) > 1) stage(1, 1); \
    for (int kt = 0; kt < (NT); ++kt) { \
        if (kt + 1 < (NT)) { WAITVM(VMID); } else { WAITVM(0); } \
        __builtin_amdgcn_s_barrier(); \
        __builtin_amdgcn_sched_barrier(0); \
        if (kt + 2 < (NT)) stage((kt + 2) % 3, kt + 2); \
        const char* base = lds + (kt % 3) * BUFB; \
        _Pragma("unroll") \
        for (int ks = 0; ks < 2; ++ks) { \
            bf16x8 afh[4], afl[4], bh, bl; \
            _Pragma("unroll") \
            for (int mi = 0; mi < ((NW2) ? 4 : 2); ++mi) { \
                int row = wm_ + mi * 16 + (l & 15); \
                int sl2 = (l >> 4) + ks * 4; \
                int off = row * 128 + ((sl2 ^ (row & 7)) << 4); \
                afh[mi] = *(const bf16x8*)(base + off); \
                afl[mi] = *(const bf16x8*)(base + APL + off); \
            } \
            { \
                int row = wn_ + (l & 15); \
                int sl2 = (l >> 4) + ks * 4; \
                int off = row * 128 + ((sl2 ^ (row & 7)) << 4); \
                bh = *(const bf16x8*)(base + 2 * APL + off); \
                bl = *(const bf16x8*)(base + 2 * APL + BPL + off); \
            } \
            _Pragma("unroll") \
            for (int mi = 0; mi < ((NW2) ? 4 : 2); ++mi) { \
                acc[mi] = __builtin_amdgcn_mfma_f32_16x16x32_bf16(afh[mi], bh, acc[mi], 0, 0, 0); \
                acc[mi] = __builtin_amdgcn_mfma_f32_16x16x32_bf16(afl[mi], bh, acc[mi], 0, 0, 0); \
                acc[mi] = __builtin_amdgcn_mfma_f32_16x16x32_bf16(afh[mi], bl, acc[mi], 0, 0, 0); \
            } \
        } \
    }

// --------------------------- G: gates GEMM + fused LSTM cell ---------------
// 128 blocks, BN=32, Ksplit=1 (NT=24). Output columns permuted c=j*4+g so each
// block owns 8 full h-columns; epilogue does the cell locally + x(t+1) split.
__global__ __launch_bounds__(256)
void gemm_g_k(const __hip_bfloat16* __restrict__ xh, const __hip_bfloat16* __restrict__ xl,
              const __hip_bfloat16* __restrict__ hh, const __hip_bfloat16* __restrict__ hl,
              const __hip_bfloat16* __restrict__ Wgh, const __hip_bfloat16* __restrict__ Wgl,
              const float* __restrict__ bsump, float* __restrict__ cbuf,
              __hip_bfloat16* __restrict__ AoBh, __hip_bfloat16* __restrict__ AoBl,
              float* __restrict__ cf,
              const float* __restrict__ input, int t,
              __hip_bfloat16* __restrict__ nxh, __hip_bfloat16* __restrict__ nxl)
{
    __shared__ __attribute__((aligned(16))) char lds[LDSZ];
    const int blk = blockIdx.x, tid = threadIdx.x;
    const int l = tid & 63, w = tid >> 6;

    GEMM_CORE(24, 1, 32, 10, blk, 0,
              xh, xl, DIN, DIN, hh, hl, H_, Wgh, Wgl, (DIN + H_));

    // ---- stage gates (bias added) into LDS, then cell ----
    __syncthreads();
    float* sg = (float*)lds;                    // [128][36] padded
    {
        float bv = bsump[n0_ + wn_ + (l & 15)];
        #pragma unroll
        for (int mi = 0; mi < 4; ++mi) {
            int rbase = wm_ + mi * 16 + (l >> 4) * 4;
            int col = wn_ + (l & 15);
            #pragma unroll
            for (int r = 0; r < 4; ++r)
                sg[(rbase + r) * 36 + col] = acc[mi][r] + bv;
        }
    }
    __syncthreads();

    #pragma unroll
    for (int k = 0; k < 4; ++k) {
        int ci = k * 256 + tid;                 // 1024 cells: 128 b x 8 j
        int b = ci >> 3, jp = ci & 7;
        float4 g4 = *(const float4*)&sg[b * 36 + jp * 4];   // i,f,g,o
        int j = blk * 8 + jp;
        long idx = (long)b * H_ + j;
        float ig = sigmoidf_(g4.x);
        float fg = sigmoidf_(g4.y);
        float gg = tanhf(g4.z);
        float og = sigmoidf_(g4.w);
        float c = fg * cbuf[idx] + ig * gg;
        float h = og * tanhf(c);
        cbuf[idx] = c;
        split_bf16(h, AoBh + (long)b * 2048 + 1024 + j, AoBl + (long)b * 2048 + 1024 + j);
        if (cf) cf[idx] = c;
    }

    // ---- split x(t+1): 128 blocks x 256 thr x 2 = 65536 ----
    if (t + 1 < T_) {
        #pragma unroll
        for (int k = 0; k < 2; ++k) {
            int i2 = blk * 512 + k * 256 + tid;
            int b2 = i2 >> 9, col = i2 & 511;
            float v = input[((long)b2 * T_ + (t + 1)) * DIN + col];
            split_bf16(v, nxh + i2, nxl + i2);
        }
    }
}

// --------------------------- Q: q partials ---------------------------------
__global__ __launch_bounds__(256)
void gemm_q_k(const __hip_bfloat16* __restrict__ AoBh, const __hip_bfloat16* __restrict__ AoBl,
              const __hip_bfloat16* __restrict__ Wah, const __hip_bfloat16* __restrict__ Wal,
              float* __restrict__ qpart)
{
    __shared__ __attribute__((aligned(16))) char lds[LDSZ];
    const int tid = threadIdx.x;
    const int l = tid & 63, w = tid >> 6;

    GEMM_CORE(4, 1, 32, 10, (int)blockIdx.x, (int)blockIdx.y,
              (AoBh + H_), (AoBl + H_), (2 * H_), H_,
              (AoBh + H_), (AoBl + H_), (2 * H_), Wah, Wal, H_);

    float* Cb = qpart + (long)blockIdx.y * (B_ * H_);
    const int n = n0_ + wn_ + (l & 15);
    #pragma unroll
    for (int mi = 0; mi < 4; ++mi) {
        int mbase = wm_ + mi * 16 + (l >> 4) * 4;
        #pragma unroll
        for (int r = 0; r < 4; ++r)
            Cb[(long)(mbase + r) * H_ + n] = acc[mi][r];
    }
}

// --------------------------- A: fused attention ----------------------------
__global__ __launch_bounds__(256)
void attn_k(const float* __restrict__ ctx, const float* __restrict__ qpart,
            const void* __restrict__ maskp, const int* __restrict__ mflag,
            __hip_bfloat16* __restrict__ AoBh, __hip_bfloat16* __restrict__ AoBl)
{
    constexpr int L = T_, H = H_;
    __shared__ float sacc[4][H_];
    __shared__ float sms[4][2];
    int b = blockIdx.x;
    const float* cb = ctx + (long)b * L * H;
    int tid = threadIdx.x, l = tid & 63, w = tid >> 6;
    int mode = mflag[0];

    float rq[16];
    #pragma unroll
    for (int j = 0; j < 16; ++j) {
        long o = (long)b * H + l + j * 64;
        rq[j] = qpart[o] + qpart[o + 131072] + qpart[o + 262144] + qpart[o + 393216];
    }

    float m = -INFINITY, s = 0.f, acc[16] = {};
    for (int li = w; li < L; li += 4) {
        bool msk = mode ? (((const int*)maskp)[b * L + li] != 0)
                        : (((const unsigned char*)maskp)[b * L + li] != 0);
        if (msk) continue;
        const float* cr = cb + (long)li * H;
        float rc[16], d = 0.f;
        #pragma unroll
        for (int j = 0; j < 16; ++j) { rc[j] = cr[l + j * 64]; d += rc[j] * rq[j]; }
        #pragma unroll
        for (int off = 1; off < 64; off <<= 1) d += __shfl_xor(d, off);
        float mn = fmaxf(m, d);
        float f = expf(m - mn);
        float p = expf(d - mn);
        s = s * f + p;
        #pragma unroll
        for (int j = 0; j < 16; ++j) acc[j] = acc[j] * f + p * rc[j];
        m = mn;
    }

    #pragma unroll
    for (int j = 0; j < 16; ++j) sacc[w][l + j * 64] = acc[j];
    if (l == 0) { sms[w][0] = m; sms[w][1] = s; }
    __syncthreads();

    float M = fmaxf(fmaxf(sms[0][0], sms[1][0]), fmaxf(sms[2][0], sms[3][0]));
    float fw[4], S = 0.f;
    #pragma unroll
    for (int ww = 0; ww < 4; ++ww) {
        fw[ww] = (sms[ww][0] == -INFINITY) ? 0.f : expf(sms[ww][0] - M);
        S += fw[ww] * sms[ww][1];
    }
    float inv = 1.f / S;
    for (int k = tid; k < H; k += 256) {
        float a = sacc[0][k] * fw[0] + sacc[1][k] * fw[1] + sacc[2][k] * fw[2] + sacc[3][k] * fw[3];
        split_bf16(a * inv, AoBh + (long)b * 2048 + k, AoBl + (long)b * 2048 + k);
    }
}

// --------------------------- O: out GEMM + fused tanh/split ----------------
// 64 blocks, BN=16, Ksplit=1 (NT=32), 4x1 wave grid. Epilogue writes h_tilde
// planes (recurrence), the fp32 output slice, and h_f at the last step.
__global__ __launch_bounds__(256)
void gemm_o_k(const __hip_bfloat16* __restrict__ AoBh, const __hip_bfloat16* __restrict__ AoBl,
              const __hip_bfloat16* __restrict__ Woh, const __hip_bfloat16* __restrict__ Wol,
              __hip_bfloat16* __restrict__ hth, __hip_bfloat16* __restrict__ htl,
              float* __restrict__ out, int t, float* __restrict__ hf)
{
    __shared__ __attribute__((aligned(16))) char lds[LDSZ];
    const int tid = threadIdx.x;
    const int l = tid & 63, w = tid >> 6;

    GEMM_CORE(32, 0, 16, 8, (int)blockIdx.x, 0,
              AoBh, AoBl, (2 * H_), (2 * H_),
              AoBh, AoBl, (2 * H_), Woh, Wol, (2 * H_));

    const int j = n0_ + (l & 15);
    #pragma unroll
    for (int mi = 0; mi < 2; ++mi) {
        int bbase = wm_ + mi * 16 + (l >> 4) * 4;
        #pragma unroll
        for (int r = 0; r < 4; ++r) {
            int b = bbase + r;
            float v = tanhf(acc[mi][r]);
            split_bf16(v, hth + (long)b * H_ + j, htl + (long)b * H_ + j);
            out[(long)b * (T_ * H_) + (long)t * H_ + j] = v;
            if (hf) hf[(long)b * H_ + j] = v;
        }
    }
}

// --------------------------- launcher --------------------------------------
extern "C" void kernel_launch(void* const* d_in, const int* in_sizes, int n_in,
                              void* d_out, int out_size, void* d_ws, size_t ws_size,
                              hipStream_t stream)
{
    const float* input  = (const float*)d_in[0];
    const float* h0     = (const float*)d_in[1];
    const float* c0     = (const float*)d_in[2];
    const float* ctx    = (const float*)d_in[3];
    const void*  srcmask= d_in[4];
    const float* W_ih   = (const float*)d_in[5];
    const float* W_hh   = (const float*)d_in[6];
    const float* b_ih   = (const float*)d_in[7];
    const float* b_hh   = (const float*)d_in[8];
    const float* W_attn = (const float*)d_in[9];
    const float* W_out  = (const float*)d_in[10];

    constexpr int B = B_, T = T_, D = DIN, H = H_;

    // -------- workspace --------
    float* f = (float*)d_ws;
    float* bsump = f; f += 4 * H;
    float* cbuf  = f; f += (size_t)B * H;
    float* qpart = f; f += (size_t)4 * B * H;
    int*   mflag = (int*)f; f += 64;
    __hip_bfloat16* p = (__hip_bfloat16*)f;
    __hip_bfloat16* Wgh = p; p += (size_t)4 * H * (D + H);
    __hip_bfloat16* Wgl = p; p += (size_t)4 * H * (D + H);
    __hip_bfloat16* Wah = p; p += (size_t)H * H;
    __hip_bfloat16* Wal = p; p += (size_t)H * H;
    __hip_bfloat16* Woh = p; p += (size_t)H * 2 * H;
    __hip_bfloat16* Wol = p; p += (size_t)H * 2 * H;
    __hip_bfloat16* hth = p; p += (size_t)B * H;       // h_tilde hi (recurrent)
    __hip_bfloat16* htl = p; p += (size_t)B * H;
    __hip_bfloat16* AoBh = p; p += (size_t)B * 2 * H;  // [wctx | hy] hi
    __hip_bfloat16* AoBl = p; p += (size_t)B * 2 * H;
    __hip_bfloat16* xth[2], *xtl[2];
    xth[0] = p; p += (size_t)B * D;
    xtl[0] = p; p += (size_t)B * D;
    xth[1] = p; p += (size_t)B * D;
    xtl[1] = p; p += (size_t)B * D;

    float* out = (float*)d_out;
    float* hf  = out + (size_t)B * T * H;
    float* cf  = hf + (size_t)B * H;

    // -------- prep --------
    hipMemcpyAsync(cbuf, c0, (size_t)B * H * sizeof(float), hipMemcpyDeviceToDevice, stream);
    bsum_perm_k<<<dim3(16), dim3(256), 0, stream>>>(b_ih, b_hh, bsump);
    detect_mask_k<<<dim3(1), dim3(256), 0, stream>>>((const int*)srcmask, B * T / 4, mflag);
    wgp_split_k<<<dim3(4 * H * (D + H) / 256), dim3(256), 0, stream>>>(W_ih, W_hh, Wgh, Wgl);
    cvt_split_k<<<dim3(H * H / 256), dim3(256), 0, stream>>>(W_attn, Wah, Wal, H * H);
    cvt_split_k<<<dim3(H * 2 * H / 256), dim3(256), 0, stream>>>(W_out, Woh, Wol, H * 2 * H);
    cvt_split_k<<<dim3(B * H / 256), dim3(256), 0, stream>>>(h0, hth, htl, B * H);
    cvtx_k<<<dim3(B * D / 256), dim3(256), 0, stream>>>(input, xth[0], xtl[0]);

    dim3 blk(256);
    for (int t = 0; t < T; ++t) {
        int sl = t & 1, sn = sl ^ 1;

        // G: gates + fused cell (+ x(t+1) split)
        gemm_g_k<<<dim3(128), blk, 0, stream>>>(
            xth[sl], xtl[sl], hth, htl, Wgh, Wgl, bsump, cbuf,
            AoBh, AoBl, (t == T - 1) ? cf : nullptr,
            input, t, xth[sn], xtl[sn]);

        // Q: q partials (Ksplit=4)
        gemm_q_k<<<dim3(32, 4), blk, 0, stream>>>(AoBh, AoBl, Wah, Wal, qpart);

        // A: attention (reduces q partials) -> wctx planes
        attn_k<<<dim3(B), blk, 0, stream>>>(ctx, qpart, srcmask, mflag, AoBh, AoBl);

        // O: out GEMM + fused tanh/split -> h_tilde planes, out slice, (h_f)
        gemm_o_k<<<dim3(64), blk, 0, stream>>>(
            AoBh, AoBl, Woh, Wol, hth, htl, out, t, (t == T - 1) ? hf : nullptr);
    }
}